// Round 1
// baseline (248.729 us; speedup 1.0000x reference)
//
#include <hip/hip_runtime.h>
#include <math.h>

#define NI   128
#define ND   32
#define NH   4
#define NNEI 120
#define KVW  ((ND + NI) * NH)   // 640, row length of Wkv
#define GGS  132                // padded LDS row stride for gg1 tile

__device__ __forceinline__ bool load_mask(const void* p, int is_i32, int idx) {
    if (is_i32) return ((const int*)p)[idx] != 0;
    return ((const unsigned char*)p)[idx] != 0;
}

__global__ __launch_bounds__(256, 2)
void local_atten_kernel(const float* __restrict__ g1,
                        const float* __restrict__ gg1,
                        const void*  __restrict__ mask_raw,
                        const float* __restrict__ sw,
                        const float* __restrict__ Wq,
                        const float* __restrict__ Wkv,
                        const float* __restrict__ Wh,
                        const float* __restrict__ bh,
                        float* __restrict__ out)
{
    __shared__ float s_gg[NNEI * GGS];      // 63360 B  gg1 tile
    __shared__ float s_g1[NI];
    __shared__ float s_q[NI];               // q * 1/sqrt(ND), layout d*NH+h
    __shared__ float s_qW[NH][NI];
    __shared__ float s_attn[NH][NNEI];
    __shared__ float s_t[NH][NI];
    __shared__ float s_ret[NH * NI];
    __shared__ float s_part[2][NI];
    __shared__ int   s_is_i32;

    const int tid = threadIdx.x;
    const int bl  = blockIdx.x;             // b*nloc + l

    // ---- mask dtype detection (deterministic: if int32, all words are 0/1) ----
    if (tid == 0) {
        const int* mi = (const int*)mask_raw;
        int ok = 1;
        for (int u = 0; u < 64; ++u) {
            unsigned v = (unsigned)mi[u];
            if (v > 1u) { ok = 0; break; }
        }
        s_is_i32 = ok;
    }

    // ---- stage g1 row + gg1 tile into LDS ----
    if (tid < NI) s_g1[tid] = g1[bl * NI + tid];
    {
        const float4* gsrc = (const float4*)(gg1 + (size_t)bl * NNEI * NI);
        for (int u = tid; u < NNEI * (NI / 4); u += 256) {
            int r  = u >> 5;        // row (neighbor)
            int c4 = u & 31;        // float4 index within row
            float4 v = gsrc[r * 32 + c4];
            float* dst = &s_gg[r * GGS + c4 * 4];
            dst[0] = v.x; dst[1] = v.y; dst[2] = v.z; dst[3] = v.w;
        }
    }
    __syncthreads();

    // ---- q[col] = (g1 . Wq[:,col]) / sqrt(ND),  col = d*NH+h ----
    if (tid < NI) {
        float acc = 0.f;
        #pragma unroll 8
        for (int i = 0; i < NI; ++i) acc += s_g1[i] * Wq[i * NI + tid];
        s_q[tid] = acc * 0.17677669529663687f;   // 1/sqrt(32)
    }
    __syncthreads();

    // ---- qW[h][i] = sum_d q[d*NH+h] * Wkv[i, d*NH+h] ----
    for (int p = 0; p < 2; ++p) {
        int o = tid + p * 256;
        int i = o & (NI - 1);
        int h = o >> 7;
        float acc = 0.f;
        #pragma unroll 8
        for (int d = 0; d < ND; ++d)
            acc += s_q[d * NH + h] * Wkv[i * KVW + d * NH + h];
        s_qW[h][i] = acc;
    }
    __syncthreads();

    // ---- logits + masked softmax + *sw, one wave per head ----
    {
        const int lane = tid & 63;
        const int h    = tid >> 6;             // 4 waves -> 4 heads
        const int j0   = lane;
        const int j1   = lane + 64;
        const int j1c  = (j1 < NNEI) ? j1 : 0; // clamp for loads

        float dot0 = 0.f, dot1 = 0.f;
        #pragma unroll 8
        for (int i = 0; i < NI; ++i) {
            float w = s_qW[h][i];
            dot0 += s_gg[j0 * GGS + i] * w;
            dot1 += s_gg[j1c * GGS + i] * w;
        }
        bool m0 = load_mask(mask_raw, s_is_i32, bl * NNEI + j0);
        bool m1 = (j1 < NNEI) && load_mask(mask_raw, s_is_i32, bl * NNEI + j1c);
        float v0 = m0 ? dot0 : -INFINITY;
        float v1 = m1 ? dot1 : -INFINITY;

        float mx = fmaxf(v0, v1);
        #pragma unroll
        for (int off = 32; off; off >>= 1) mx = fmaxf(mx, __shfl_xor(mx, off));

        float e0 = 0.f, e1 = 0.f;
        if (mx != -INFINITY) {
            e0 = m0 ? __expf(v0 - mx) : 0.f;
            e1 = m1 ? __expf(v1 - mx) : 0.f;
        }
        float s = e0 + e1;
        #pragma unroll
        for (int off = 32; off; off >>= 1) s += __shfl_xor(s, off);
        float inv = (s > 0.f) ? (1.f / s) : 0.f;

        s_attn[h][j0] = e0 * inv * sw[bl * NNEI + j0];
        if (j1 < NNEI) s_attn[h][j1] = e1 * inv * sw[bl * NNEI + j1];
    }
    __syncthreads();

    // ---- t[h][i] = sum_j attn[h][j] * gg1[j][i] ----
    for (int p = 0; p < 2; ++p) {
        int o = tid + p * 256;
        int i = o & (NI - 1);
        int h = o >> 7;
        float acc = 0.f;
        #pragma unroll 8
        for (int j = 0; j < NNEI; ++j)
            acc += s_attn[h][j] * s_gg[j * GGS + i];
        s_t[h][i] = acc;
    }
    __syncthreads();

    // ---- ret[h][iv] = sum_i t[h][i] * Wkv[i, (ND+iv)*NH + h] ----
    for (int p = 0; p < 2; ++p) {
        int o  = tid + p * 256;
        int iv = o & (NI - 1);
        int h  = o >> 7;
        float acc = 0.f;
        #pragma unroll 8
        for (int i = 0; i < NI; ++i)
            acc += s_t[h][i] * Wkv[i * KVW + (ND + iv) * NH + h];
        s_ret[h * NI + iv] = acc;
    }
    __syncthreads();

    // ---- out[io] = sum_hi ret[hi] * Wh[hi, io] + bh[io], split over 2 halves ----
    {
        int io   = tid & (NI - 1);
        int half = tid >> 7;
        float acc = 0.f;
        #pragma unroll 8
        for (int hi = half * 256; hi < half * 256 + 256; ++hi)
            acc += s_ret[hi] * Wh[hi * NI + io];
        s_part[half][io] = acc;
    }
    __syncthreads();
    if (tid < NI)
        out[bl * NI + tid] = s_part[0][tid] + s_part[1][tid] + bh[tid];
}

extern "C" void kernel_launch(void* const* d_in, const int* in_sizes, int n_in,
                              void* d_out, int out_size, void* d_ws, size_t ws_size,
                              hipStream_t stream) {
    const float* g1   = (const float*)d_in[0];
    const float* gg1  = (const float*)d_in[1];
    const void*  mask = d_in[2];
    const float* sw   = (const float*)d_in[3];
    const float* Wq   = (const float*)d_in[4];
    const float* Wkv  = (const float*)d_in[5];
    const float* Wh   = (const float*)d_in[6];
    const float* bh   = (const float*)d_in[7];
    float* out = (float*)d_out;

    const int nbl = in_sizes[0] / NI;   // nb * nloc = 2048
    local_atten_kernel<<<nbl, 256, 0, stream>>>(g1, gg1, mask, sw, Wq, Wkv, Wh, bh, out);
}

// Round 2
// 127.130 us; speedup vs baseline: 1.9565x; 1.9565x over previous
//
#include <hip/hip_runtime.h>
#include <math.h>

#define NI   128
#define ND   32
#define NH   4
#define NNEI 120
#define KVW  ((ND + NI) * NH)   // 640
#define GGS  129                // padded LDS row stride: 129%32==1 -> conflict-free column reads

// ---------------- precompute kernel: fold weights once per launch ----------------
// M[h][i2][i] = (1/sqrt(ND)) * sum_d Wq[i2, d*NH+h] * Wkv[i, d*NH+h]      (q @ k^T combined)
// P[h][i][io] = sum_iv Wkv[i, (ND+iv)*NH+h] * Wh[h*NI+iv, io]             (v-proj @ Wh combined)
__global__ __launch_bounds__(256)
void precompute_MP(const float* __restrict__ Wq, const float* __restrict__ Wkv,
                   const float* __restrict__ Wh, float* __restrict__ M, float* __restrict__ P)
{
    int idx = blockIdx.x * 256 + threadIdx.x;       // 512 blocks -> 131072 threads
    if (idx < NH * NI * NI) {                       // M part
        int i  = idx & (NI - 1);
        int i2 = (idx >> 7) & (NI - 1);
        int h  = idx >> 14;
        float acc = 0.f;
        #pragma unroll 8
        for (int d = 0; d < ND; ++d)
            acc += Wq[i2 * NI + d * NH + h] * Wkv[i * KVW + d * NH + h];
        M[idx] = acc * 0.17677669529663687f;        // 1/sqrt(32)
    } else {                                        // P part
        int j  = idx - NH * NI * NI;
        int io = j & (NI - 1);
        int i  = (j >> 7) & (NI - 1);
        int h  = j >> 14;
        float acc = 0.f;
        #pragma unroll 8
        for (int iv = 0; iv < NI; ++iv)
            acc += Wkv[i * KVW + (ND + iv) * NH + h] * Wh[(h * NI + iv) * NI + io];
        P[j] = acc;
    }
}

__device__ __forceinline__ bool load_mask(const void* p, int is_i32, int idx) {
    if (is_i32) return ((const int*)p)[idx] != 0;
    return ((const unsigned char*)p)[idx] != 0;
}

__global__ __launch_bounds__(256, 2)
void local_atten_kernel(const float* __restrict__ g1,
                        const float* __restrict__ gg1,
                        const void*  __restrict__ mask_raw,
                        const float* __restrict__ sw,
                        const float* __restrict__ M,
                        const float* __restrict__ P,
                        const float* __restrict__ bh,
                        float* __restrict__ out)
{
    __shared__ float s_gg[NNEI * GGS];      // 61,920 B
    __shared__ float s_qW[NH][NI];
    __shared__ float s_attn[NH][NNEI];
    __shared__ float s_t[NH][NI];
    __shared__ float s_part[2][NI];
    __shared__ int   s_is_i32;

    const int tid = threadIdx.x;
    const int bl  = blockIdx.x;

    if (tid == 0) {
        const int* mi = (const int*)mask_raw;
        int ok = 1;
        for (int u = 0; u < 64; ++u) {
            unsigned v = (unsigned)mi[u];
            if (v > 1u) { ok = 0; break; }
        }
        s_is_i32 = ok;
    }

    // ---- stage gg1 tile (coalesced float4 -> padded LDS rows) ----
    {
        const float4* gsrc = (const float4*)(gg1 + (size_t)bl * NNEI * NI);
        #pragma unroll
        for (int p = 0; p < 15; ++p) {
            int u  = tid + p * 256;
            int r  = u >> 5;          // neighbor row
            int c4 = u & 31;          // float4 within row
            float4 v = gsrc[u];
            float* dst = &s_gg[r * GGS + c4 * 4];
            dst[0] = v.x; dst[1] = v.y; dst[2] = v.z; dst[3] = v.w;
        }
    }

    // ---- qW[h][i] = sum_i2 g1[i2] * M[h][i2][i]  (g1: wave-uniform scalar loads; M coalesced) ----
    {
        const float* g1r = g1 + bl * NI;
        #pragma unroll
        for (int p = 0; p < 2; ++p) {
            int o = tid + p * 256;
            int i = o & (NI - 1);
            int h = o >> 7;
            const float* Mp = M + h * NI * NI + i;
            float acc = 0.f;
            #pragma unroll 8
            for (int i2 = 0; i2 < NI; ++i2)
                acc += g1r[i2] * Mp[i2 * NI];
            s_qW[h][i] = acc;
        }
    }
    __syncthreads();

    // ---- logits + masked softmax + *sw : one wave per head ----
    {
        const int lane = tid & 63;
        const int h    = tid >> 6;
        const int j0   = lane;
        const int j1   = lane + 64;
        const int j1c  = (j1 < NNEI) ? j1 : 0;

        const float* row0 = &s_gg[j0 * GGS];
        const float* row1 = &s_gg[j1c * GGS];
        float dot0 = 0.f, dot1 = 0.f;
        #pragma unroll 8
        for (int i = 0; i < NI; ++i) {
            float w = s_qW[h][i];
            dot0 += row0[i] * w;
            dot1 += row1[i] * w;
        }
        bool m0 = load_mask(mask_raw, s_is_i32, bl * NNEI + j0);
        bool m1 = (j1 < NNEI) && load_mask(mask_raw, s_is_i32, bl * NNEI + j1c);
        float v0 = m0 ? dot0 : -INFINITY;
        float v1 = m1 ? dot1 : -INFINITY;

        float mx = fmaxf(v0, v1);
        #pragma unroll
        for (int off = 32; off; off >>= 1) mx = fmaxf(mx, __shfl_xor(mx, off));

        float e0 = 0.f, e1 = 0.f;
        if (mx != -INFINITY) {
            e0 = m0 ? __expf(v0 - mx) : 0.f;
            e1 = m1 ? __expf(v1 - mx) : 0.f;
        }
        float s = e0 + e1;
        #pragma unroll
        for (int off = 32; off; off >>= 1) s += __shfl_xor(s, off);
        float inv = (s > 0.f) ? (1.f / s) : 0.f;

        s_attn[h][j0] = e0 * inv * sw[bl * NNEI + j0];
        if (j1 < NNEI) s_attn[h][j1] = e1 * inv * sw[bl * NNEI + j1];
    }
    __syncthreads();

    // ---- t[h][i] = sum_j attn[h][j] * gg1[j][i]   (attn broadcast, gg conflict-free) ----
    #pragma unroll
    for (int p = 0; p < 2; ++p) {
        int o = tid + p * 256;
        int i = o & (NI - 1);
        int h = o >> 7;
        float acc = 0.f;
        #pragma unroll 8
        for (int j = 0; j < NNEI; ++j)
            acc += s_attn[h][j] * s_gg[j * GGS + i];
        s_t[h][i] = acc;
    }
    __syncthreads();

    // ---- out[io] = bh[io] + sum_h sum_i t[h][i] * P[h][i][io]  (P coalesced, t broadcast) ----
    {
        int io   = tid & (NI - 1);
        int half = tid >> 7;
        float acc = 0.f;
        #pragma unroll 2
        for (int h = half * 2; h < half * 2 + 2; ++h) {
            const float* Pp = P + h * NI * NI + io;
            #pragma unroll 8
            for (int i = 0; i < NI; ++i)
                acc += s_t[h][i] * Pp[i * NI];
        }
        s_part[half][io] = acc;
    }
    __syncthreads();
    if (tid < NI)
        out[bl * NI + tid] = s_part[0][tid] + s_part[1][tid] + bh[tid];
}

extern "C" void kernel_launch(void* const* d_in, const int* in_sizes, int n_in,
                              void* d_out, int out_size, void* d_ws, size_t ws_size,
                              hipStream_t stream) {
    const float* g1   = (const float*)d_in[0];
    const float* gg1  = (const float*)d_in[1];
    const void*  mask = d_in[2];
    const float* sw   = (const float*)d_in[3];
    const float* Wq   = (const float*)d_in[4];
    const float* Wkv  = (const float*)d_in[5];
    const float* Wh   = (const float*)d_in[6];
    const float* bh   = (const float*)d_in[7];
    float* out = (float*)d_out;

    float* M = (float*)d_ws;                     // NH*NI*NI floats = 256 KB
    float* P = M + NH * NI * NI;                 // NH*NI*NI floats = 256 KB

    precompute_MP<<<512, 256, 0, stream>>>(Wq, Wkv, Wh, M, P);

    const int nbl = in_sizes[0] / NI;            // nb * nloc = 2048
    local_atten_kernel<<<nbl, 256, 0, stream>>>(g1, gg1, mask, sw, M, P, bh, out);
}